// Round 6
// baseline (452.097 us; speedup 1.0000x reference)
//
#include <hip/hip_runtime.h>
#include <stdint.h>

// CMAALayer fused kernel, MI355X gfx950. Round 9.
// R8 post-mortem: 2 blocks/CU = -3%. Four structural reorgs all ~270us,
// no pipe >25%. Only weight-path changes ever moved time (R6 +30%, R7 +90%)
// -> dependent L2 weight-load chains are the critical path; at VGPR=64 the
// compiler pipelines only ~2 kk ahead. Round 9 = deep per-wave MLP:
//   - __launch_bounds__(512,2): 256-VGPR budget. Each GEMM pass prefetches
//     its ENTIRE weight slice to regs (w0/w1[2][8] = 128 VGPR, 32 loads
//     in flight, one latency exposure). Wo frags issued at end of pass-1
//     GEMM, in flight across softmax/PV/barriers.
//   - Coalesced attn-prob store: softmax -> fp32 alpha (l-order) in 6KB LDS;
//     384 threads copy out as float4 (fixes R8's 143->230MB write
//     amplification from scattered 12B stores). PV maps m->l on read.
//   - Keeps R8: wave=head swapped-operand GEMM, in-reg sigmoid*V, shfl-xor
//     scores/PV (neighbors = lane^m), AO in LDS, reg-LN with partial
//     exchange. Grid 2048 lockstep (weight L2 reuse mechanism, R7 lesson).
// LDS: sX 33.8K + sAO 33.8K + sALf 6K + sPT 5K = 78.8K (1 block/CU; VGPR-
// limited to 2 waves/SIMD anyway - trading TLP for MLP, R4/R5 showed TLP
// is not binding).

#define D_DIM   256
#define H_NUM   8
#define RT      64
#define NTHR    512
#define ROWS_TOT 131072
#define Y_SZ    33554432          // 131072*256
#define SCALE_F 0.17677669529663687f
#define W_ELEMS 65536             // 256*256 per matrix
#define WS_NEED (5 * W_ELEMS * 2) // bytes for bf16 weight copy

#define SX_LD   264   // shorts; 528B row stride
#define AO_LD   264
#define SP_LD   20    // floats; 80B row stride

typedef __attribute__((ext_vector_type(8))) short bf16x8;
typedef __attribute__((ext_vector_type(4))) float f32x4;

__device__ __forceinline__ float b2f(uint16_t s) {
    union { uint32_t u; float f; } c; c.u = ((uint32_t)s) << 16; return c.f;
}
__device__ __forceinline__ uint16_t f2b(float f) {
    union { float f; uint32_t u; } c; c.f = f;
    return (uint16_t)((c.u + 0x7fffu + ((c.u >> 16) & 1u)) >> 16);
}
__device__ __forceinline__ bf16x8 cvt8(const float* p) {
    const float4 a = *(const float4*)p;
    const float4 b = *(const float4*)(p + 4);
    bf16x8 r;
    r[0] = (short)f2b(a.x); r[1] = (short)f2b(a.y);
    r[2] = (short)f2b(a.z); r[3] = (short)f2b(a.w);
    r[4] = (short)f2b(b.x); r[5] = (short)f2b(b.y);
    r[6] = (short)f2b(b.z); r[7] = (short)f2b(b.w);
    return r;
}
__device__ __forceinline__ uint2 pack4(f32x4 a) {
    uint2 p;
    p.x = (uint32_t)f2b(a[0]) | ((uint32_t)f2b(a[1]) << 16);
    p.y = (uint32_t)f2b(a[2]) | ((uint32_t)f2b(a[3]) << 16);
    return p;
}

// ---------------- K0: weight fp32 -> bf16 conversion ----------------
__global__ __launch_bounds__(256)
void conv_weights(const float* __restrict__ Wq, const float* __restrict__ Wk,
                  const float* __restrict__ Wv, const float* __restrict__ Wr,
                  const float* __restrict__ Wo, uint16_t* __restrict__ dst)
{
    const int m = blockIdx.x >> 6;                 // matrix id 0..4
    const float* src = (m == 0) ? Wq : (m == 1) ? Wk : (m == 2) ? Wv
                     : (m == 3) ? Wr : Wo;
    const int base = (blockIdx.x & 63) * 1024 + threadIdx.x * 4;
    const float4 v = *(const float4*)&src[base];
    uint2 pk;
    pk.x = (uint32_t)f2b(v.x) | ((uint32_t)f2b(v.y) << 16);
    pk.y = (uint32_t)f2b(v.z) | ((uint32_t)f2b(v.w) << 16);
    *(uint2*)&dst[(size_t)m * W_ELEMS + base] = pk;
}

// ---------------- K1: fused layer ----------------
template<bool WBF16>
__global__ __launch_bounds__(NTHR, 2)
void cmaa_fused(const float* __restrict__ tok,
                const float* __restrict__ Wq, const float* __restrict__ Wk,
                const float* __restrict__ Wv, const float* __restrict__ Wr,
                const float* __restrict__ Wo,
                const uint16_t* __restrict__ wbf,
                const float* __restrict__ lng, const float* __restrict__ lnb,
                float* __restrict__ outp)
{
    __shared__ __align__(16) uint16_t sX  [RT * SX_LD];      // 33792 B
    __shared__ __align__(16) uint16_t sAO [RT * AO_LD];      // 33792 B
    __shared__ __align__(16) float    sALf[RT * H_NUM * 3];  // 6144 B: alpha fp32, l-order
    __shared__ __align__(16) float    sPT [RT * SP_LD];      // 5120 B: LN partials

    const int tid  = threadIdx.x;
    const int wv   = tid >> 6;        // wave 0..7
    const int lane = tid & 63;
    const int l15  = lane & 15;
    const int quad = lane >> 4;
    const int R0   = blockIdx.x * RT;

    // ---------------- stage 0: X tile -> LDS (bf16) ----------------
    {
        const float* g = tok + (size_t)R0 * D_DIM;
        #pragma unroll
        for (int it = 0; it < 4; ++it) {
            const int t = tid + it * NTHR;
            const int row = t >> 5, c = t & 31;
            *(bf16x8*)&sX[row * SX_LD + c * 8] = cvt8(&g[row * D_DIM + c * 8]);
        }
    }
    __syncthreads();

    const bool qk = (wv < 4);
    const int  hl = wv & 3;

    bf16x8 wo_reg[2][8];   // Wo fragments, issued at end of p==1 GEMM

    #pragma unroll
    for (int p = 0; p < 2; ++p) {
        const int h = p * 4 + hl;          // this wave's head for this pass
        const int colbase = h * 32;
        const float*    WF0 = qk ? Wq : Wv;
        const float*    WF1 = qk ? Wk : Wr;
        const uint16_t* WB0 = wbf + (size_t)(qk ? 0 : 2) * W_ELEMS;
        const uint16_t* WB1 = WB0 + W_ELEMS;

        // ---------- deep prefetch: ALL weight frags for this pass ----------
        bf16x8 w0[2][8], w1[2][8];
        #pragma unroll
        for (int ct = 0; ct < 2; ++ct) {
            const int wrow = colbase + ct * 16 + l15;
            #pragma unroll
            for (int kk = 0; kk < 8; ++kk) {
                if constexpr (WBF16) {
                    w0[ct][kk] = *(const bf16x8*)&WB0[(size_t)wrow * D_DIM + kk * 32 + quad * 8];
                    w1[ct][kk] = *(const bf16x8*)&WB1[(size_t)wrow * D_DIM + kk * 32 + quad * 8];
                } else {
                    w0[ct][kk] = cvt8(&WF0[(size_t)wrow * D_DIM + kk * 32 + quad * 8]);
                    w1[ct][kk] = cvt8(&WF1[(size_t)wrow * D_DIM + kk * 32 + quad * 8]);
                }
            }
        }

        // ---------- projection GEMM (swapped operands) ----------
        // acc[m][ct][nt][r] = proj[out-dim colbase+ct*16+quad*4+r][token nt*16+l15]
        f32x4 acc[2][2][4];
        #pragma unroll
        for (int m = 0; m < 2; ++m)
            #pragma unroll
            for (int ct = 0; ct < 2; ++ct)
                #pragma unroll
                for (int nt = 0; nt < 4; ++nt)
                    acc[m][ct][nt] = (f32x4){0.f, 0.f, 0.f, 0.f};

        #pragma unroll
        for (int kk = 0; kk < 8; ++kk) {
            const int k0 = kk * 32;
            bf16x8 ax[4];
            #pragma unroll
            for (int nt = 0; nt < 4; ++nt)
                ax[nt] = *(const bf16x8*)&sX[(nt * 16 + l15) * SX_LD + k0 + quad * 8];
            #pragma unroll
            for (int ct = 0; ct < 2; ++ct)
                #pragma unroll
                for (int nt = 0; nt < 4; ++nt)
                    acc[0][ct][nt] = __builtin_amdgcn_mfma_f32_16x16x32_bf16(w0[ct][kk], ax[nt], acc[0][ct][nt], 0, 0, 0);
            #pragma unroll
            for (int ct = 0; ct < 2; ++ct)
                #pragma unroll
                for (int nt = 0; nt < 4; ++nt)
                    acc[1][ct][nt] = __builtin_amdgcn_mfma_f32_16x16x32_bf16(w1[ct][kk], ax[nt], acc[1][ct][nt], 0, 0, 0);
        }

        if (p == 1) {
            // issue Wo loads now; in flight across softmax/PV/barriers
            const uint16_t* WoB = wbf + (size_t)4 * W_ELEMS;
            #pragma unroll
            for (int ct = 0; ct < 2; ++ct) {
                const int wrow = wv * 32 + ct * 16 + l15;
                #pragma unroll
                for (int kk = 0; kk < 8; ++kk) {
                    if constexpr (WBF16)
                        wo_reg[ct][kk] = *(const bf16x8*)&WoB[(size_t)wrow * D_DIM + kk * 32 + quad * 8];
                    else
                        wo_reg[ct][kk] = cvt8(&Wo[(size_t)wrow * D_DIM + kk * 32 + quad * 8]);
                }
            }
        }

        if (qk) {
            // ---------- scores + softmax, fully in-wave ----------
            // neighbor j of token i is i^m (m=1..3); 4-group = 4 adjacent lanes
            #pragma unroll
            for (int nt = 0; nt < 4; ++nt) {
                float sc[3];
                #pragma unroll
                for (int m = 1; m <= 3; ++m) {
                    float s = 0.f;
                    #pragma unroll
                    for (int ct = 0; ct < 2; ++ct)
                        #pragma unroll
                        for (int r = 0; r < 4; ++r)
                            s += acc[0][ct][nt][r] * __shfl_xor(acc[1][ct][nt][r], m);
                    s += __shfl_xor(s, 16);      // reduce over quads
                    s += __shfl_xor(s, 32);
                    sc[m - 1] = s * SCALE_F;
                }
                const float mx = fmaxf(sc[0], fmaxf(sc[1], sc[2]));
                const float e1 = __expf(sc[0] - mx), e2 = __expf(sc[1] - mx), e3 = __expf(sc[2] - mx);
                const float inv = 1.f / (e1 + e2 + e3);
                const float am[3] = { e1 * inv, e2 * inv, e3 * inv };   // m-order
                const int token = nt * 16 + l15;
                if (quad == 0) {
                    // store in reference l-order: jj = l + (l>=ii), m = ii^jj
                    const int ii = token & 3;
                    float* al = &sALf[(token * H_NUM + h) * 3];
                    #pragma unroll
                    for (int l = 0; l < 3; ++l) {
                        const int jj = l + (l >= ii);
                        const int m  = ii ^ jj;
                        al[l] = am[m - 1];
                    }
                }
            }
        } else {
            // ---------- V_eff = sigmoid(R)*V in regs ----------
            #pragma unroll
            for (int ct = 0; ct < 2; ++ct)
                #pragma unroll
                for (int nt = 0; nt < 4; ++nt)
                    #pragma unroll
                    for (int r = 0; r < 4; ++r)
                        acc[0][ct][nt][r] *= 1.f / (1.f + __expf(-acc[1][ct][nt][r]));
        }
        __syncthreads();   // alphas visible to V-waves

        if (!qk) {
            // ---------- PV via shuffles -> AO to LDS ----------
            #pragma unroll
            for (int nt = 0; nt < 4; ++nt) {
                const int token = nt * 16 + l15;
                const int ii = token & 3;
                const float* al = &sALf[(token * H_NUM + h) * 3];
                float am[3];   // m-order from l-order
                #pragma unroll
                for (int m = 1; m <= 3; ++m) {
                    const int jj = ii ^ m;
                    const int l  = jj - (jj > ii ? 1 : 0);
                    am[m - 1] = al[l];
                }
                #pragma unroll
                for (int ct = 0; ct < 2; ++ct) {
                    f32x4 ao;
                    #pragma unroll
                    for (int r = 0; r < 4; ++r) {
                        const float v = acc[0][ct][nt][r];
                        ao[r] = am[0] * __shfl_xor(v, 1)
                              + am[1] * __shfl_xor(v, 2)
                              + am[2] * __shfl_xor(v, 3);
                    }
                    *(uint2*)&sAO[token * AO_LD + colbase + ct * 16 + quad * 4] = pack4(ao);
                }
            }
        }
        __syncthreads();   // pass done
    }

    // ---------------- coalesced attn-prob store (fp32, contiguous) ----------
    if (tid < 384) {
        const float4 v = *(const float4*)&sALf[tid * 4];
        *(float4*)&outp[Y_SZ + (size_t)R0 * (H_NUM * 3) + tid * 4] = v;
    }

    // ---------------- AO @ Wo^T (weights already in regs) ----------------
    f32x4 acc3[2][4];   // [ct][nt]: out-col wv*32+ct*16+quad*4+r, token nt*16+l15
    #pragma unroll
    for (int ct = 0; ct < 2; ++ct)
        #pragma unroll
        for (int nt = 0; nt < 4; ++nt)
            acc3[ct][nt] = (f32x4){0.f, 0.f, 0.f, 0.f};

    #pragma unroll
    for (int kk = 0; kk < 8; ++kk) {
        const int k0 = kk * 32;
        bf16x8 ao[4];
        #pragma unroll
        for (int nt = 0; nt < 4; ++nt)
            ao[nt] = *(const bf16x8*)&sAO[(nt * 16 + l15) * AO_LD + k0 + quad * 8];
        #pragma unroll
        for (int ct = 0; ct < 2; ++ct)
            #pragma unroll
            for (int nt = 0; nt < 4; ++nt)
                acc3[ct][nt] = __builtin_amdgcn_mfma_f32_16x16x32_bf16(wo_reg[ct][kk], ao[nt], acc3[ct][nt], 0, 0, 0);
    }

    // ---------------- residual + LN partials (in regs) ----------------
    #pragma unroll
    for (int nt = 0; nt < 4; ++nt) {
        const int token = nt * 16 + l15;
        float s1 = 0.f, s2 = 0.f;
        #pragma unroll
        for (int ct = 0; ct < 2; ++ct) {
            const ushort4 xv = *(const ushort4*)&sX[token * SX_LD + wv * 32 + ct * 16 + quad * 4];
            const float x0 = b2f(xv.x), x1 = b2f(xv.y), x2 = b2f(xv.z), x3 = b2f(xv.w);
            acc3[ct][nt][0] += x0; acc3[ct][nt][1] += x1;
            acc3[ct][nt][2] += x2; acc3[ct][nt][3] += x3;
            #pragma unroll
            for (int r = 0; r < 4; ++r) {
                const float y = acc3[ct][nt][r];
                s1 += y; s2 += y * y;
            }
        }
        s1 += __shfl_xor(s1, 16); s1 += __shfl_xor(s1, 32);
        s2 += __shfl_xor(s2, 16); s2 += __shfl_xor(s2, 32);
        if (quad == 0) {
            float2 ps; ps.x = s1; ps.y = s2;
            *(float2*)&sPT[token * SP_LD + wv * 2] = ps;
        }
    }
    __syncthreads();

    // ---------------- LN finalize + store y from regs ----------------
    #pragma unroll
    for (int nt = 0; nt < 4; ++nt) {
        const int token = nt * 16 + l15;
        const f32x4* pp = (const f32x4*)&sPT[token * SP_LD];
        const f32x4 q0 = pp[0], q1 = pp[1], q2 = pp[2], q3 = pp[3];
        const float s1 = q0[0] + q0[2] + q1[0] + q1[2] + q2[0] + q2[2] + q3[0] + q3[2];
        const float s2 = q0[1] + q0[3] + q1[1] + q1[3] + q2[1] + q2[3] + q3[1] + q3[3];
        const float mean = s1 * (1.f / 256.f);
        const float var  = fmaxf(s2 * (1.f / 256.f) - mean * mean, 0.f);
        const float rstd = rsqrtf(var + 1e-5f);
        float* orow = outp + (size_t)(R0 + token) * D_DIM;
        #pragma unroll
        for (int ct = 0; ct < 2; ++ct) {
            const int c0 = wv * 32 + ct * 16 + quad * 4;
            const float4 g4 = *(const float4*)&lng[c0];
            const float4 b4 = *(const float4*)&lnb[c0];
            float4 o4;
            o4.x = (acc3[ct][nt][0] - mean) * rstd * g4.x + b4.x;
            o4.y = (acc3[ct][nt][1] - mean) * rstd * g4.y + b4.y;
            o4.z = (acc3[ct][nt][2] - mean) * rstd * g4.z + b4.z;
            o4.w = (acc3[ct][nt][3] - mean) * rstd * g4.w + b4.w;
            *(float4*)&orow[c0] = o4;
        }
    }
}

extern "C" void kernel_launch(void* const* d_in, const int* in_sizes, int n_in,
                              void* d_out, int out_size, void* d_ws, size_t ws_size,
                              hipStream_t stream) {
    (void)in_sizes; (void)n_in; (void)out_size;
    const float* tok = (const float*)d_in[0];
    const float* Wq  = (const float*)d_in[1];
    const float* Wk  = (const float*)d_in[2];
    const float* Wv  = (const float*)d_in[3];
    const float* Wr  = (const float*)d_in[4];
    const float* Wo  = (const float*)d_in[5];
    const float* lng = (const float*)d_in[6];
    const float* lnb = (const float*)d_in[7];
    float* outp = (float*)d_out;
    uint16_t* wbf = (uint16_t*)d_ws;

    dim3 grid(ROWS_TOT / RT), block(NTHR);
    if (ws_size >= (size_t)WS_NEED) {
        conv_weights<<<dim3(320), dim3(256), 0, stream>>>(Wq, Wk, Wv, Wr, Wo, wbf);
        cmaa_fused<true><<<grid, block, 0, stream>>>(
            tok, Wq, Wk, Wv, Wr, Wo, wbf, lng, lnb, outp);
    } else {
        cmaa_fused<false><<<grid, block, 0, stream>>>(
            tok, Wq, Wk, Wv, Wr, Wo, wbf, lng, lnb, outp);
    }
}

// Round 7
// 414.907 us; speedup vs baseline: 1.0896x; 1.0896x over previous
//
#include <hip/hip_runtime.h>
#include <stdint.h>

// CMAALayer fused kernel, MI355X gfx950. Round 10.
// R9 post-mortem: deep prefetch defeated by compiler (VGPR 84, loads sunk);
// occupancy fell to 1 blk/CU; +23us. Six-round synthesis: ONLY weight-path
// changes move time (R6 +82us for +1.3GB L2; R7 +251us cold). Phase sum
// 36(MFMA)+60(VALU)+50(LDS)+80(weights-L2)+45(HBM) ~= 270 = measured.
// Round 10 halves the weight-L2 addend:
//   - grid 1024, 2 consecutive 64-row tiles per block. Per pass, each wave's
//     QKVR slice (w0/w1[2][8]=128 VGPR) is loaded ONCE and register-resident
//     across BOTH tiles' GEMMs; Wo loaded once for both tiles in epilogue.
//     Weight L2 traffic 1.31 GB -> 0.66 GB. Tiles are back-to-back so L2
//     stays lockstep-warm (R7's eviction gap doesn't open).
//   - Free phase mixing: V-waves run PV(tile0) in the same barrier region as
//     GEMM(tile1) issue; barriers ~10 -> 7 per 2 tiles.
//   - Keeps R8/R9 verified parts: wave=(role,head) swapped-operand GEMM,
//     in-reg sigmoid*V, shfl-xor scores/PV (neighbors = lane^m), l-order
//     alpha in LDS + coalesced fp32 prob store, reg-LN with partial exchange.
// LDS: 2*(sX 33.8K + sAO 33.8K) + alpha 12K + partials 10K = 157.7 KB.
// 512 thr, __launch_bounds__(512,2): VGPR budget 256, expect ~230.

#define D_DIM   256
#define H_NUM   8
#define RT      64
#define NTHR    512
#define ROWS_TOT 131072
#define Y_SZ    33554432          // 131072*256
#define SCALE_F 0.17677669529663687f
#define W_ELEMS 65536             // 256*256 per matrix
#define WS_NEED (5 * W_ELEMS * 2) // bytes for bf16 weight copy

#define SX_LD   264   // shorts; 528B row stride
#define AO_LD   264
#define SP_LD   20    // floats; 80B row stride

typedef __attribute__((ext_vector_type(8))) short bf16x8;
typedef __attribute__((ext_vector_type(4))) float f32x4;

__device__ __forceinline__ float b2f(uint16_t s) {
    union { uint32_t u; float f; } c; c.u = ((uint32_t)s) << 16; return c.f;
}
__device__ __forceinline__ uint16_t f2b(float f) {
    union { float f; uint32_t u; } c; c.f = f;
    return (uint16_t)((c.u + 0x7fffu + ((c.u >> 16) & 1u)) >> 16);
}
__device__ __forceinline__ bf16x8 cvt8(const float* p) {
    const float4 a = *(const float4*)p;
    const float4 b = *(const float4*)(p + 4);
    bf16x8 r;
    r[0] = (short)f2b(a.x); r[1] = (short)f2b(a.y);
    r[2] = (short)f2b(a.z); r[3] = (short)f2b(a.w);
    r[4] = (short)f2b(b.x); r[5] = (short)f2b(b.y);
    r[6] = (short)f2b(b.z); r[7] = (short)f2b(b.w);
    return r;
}
__device__ __forceinline__ uint2 pack4(f32x4 a) {
    uint2 p;
    p.x = (uint32_t)f2b(a[0]) | ((uint32_t)f2b(a[1]) << 16);
    p.y = (uint32_t)f2b(a[2]) | ((uint32_t)f2b(a[3]) << 16);
    return p;
}

// ---------------- K0: weight fp32 -> bf16 conversion ----------------
__global__ __launch_bounds__(256)
void conv_weights(const float* __restrict__ Wq, const float* __restrict__ Wk,
                  const float* __restrict__ Wv, const float* __restrict__ Wr,
                  const float* __restrict__ Wo, uint16_t* __restrict__ dst)
{
    const int m = blockIdx.x >> 6;                 // matrix id 0..4
    const float* src = (m == 0) ? Wq : (m == 1) ? Wk : (m == 2) ? Wv
                     : (m == 3) ? Wr : Wo;
    const int base = (blockIdx.x & 63) * 1024 + threadIdx.x * 4;
    const float4 v = *(const float4*)&src[base];
    uint2 pk;
    pk.x = (uint32_t)f2b(v.x) | ((uint32_t)f2b(v.y) << 16);
    pk.y = (uint32_t)f2b(v.z) | ((uint32_t)f2b(v.w) << 16);
    *(uint2*)&dst[(size_t)m * W_ELEMS + base] = pk;
}

// ---------------- K1: fused layer, 2 tiles/block ----------------
template<bool WBF16>
__global__ __launch_bounds__(NTHR, 2)
void cmaa_fused(const float* __restrict__ tok,
                const float* __restrict__ Wq, const float* __restrict__ Wk,
                const float* __restrict__ Wv, const float* __restrict__ Wr,
                const float* __restrict__ Wo,
                const uint16_t* __restrict__ wbf,
                const float* __restrict__ lng, const float* __restrict__ lnb,
                float* __restrict__ outp)
{
    __shared__ __align__(16) uint16_t sX  [2][RT * SX_LD];      // 67584 B
    __shared__ __align__(16) uint16_t sAO [2][RT * AO_LD];      // 67584 B
    __shared__ __align__(16) float    sALf[2][RT * H_NUM * 3];  // 12288 B
    __shared__ __align__(16) float    sPT [2][RT * SP_LD];      // 10240 B

    const int tid  = threadIdx.x;
    const int wv   = tid >> 6;        // wave 0..7
    const int lane = tid & 63;
    const int l15  = lane & 15;
    const int quad = lane >> 4;
    const int R0   = blockIdx.x * (2 * RT);

    // ---------------- stage 0: both X tiles -> LDS (bf16) ----------------
    {
        const float* g = tok + (size_t)R0 * D_DIM;
        #pragma unroll
        for (int it = 0; it < 8; ++it) {
            const int t   = tid + it * NTHR;
            const int row = t >> 5;          // 0..127
            const int c   = t & 31;
            const int tl  = row >> 6;
            const int rin = row & 63;
            *(bf16x8*)&sX[tl][rin * SX_LD + c * 8] = cvt8(&g[row * D_DIM + c * 8]);
        }
    }
    __syncthreads();

    const bool qk = (wv < 4);
    const int  hl = wv & 3;

    for (int p = 0; p < 2; ++p) {
        const int h = p * 4 + hl;
        const int colbase = h * 32;
        const float*    WF0 = qk ? Wq : Wv;
        const float*    WF1 = qk ? Wk : Wr;
        const uint16_t* WB0 = wbf + (size_t)(qk ? 0 : 2) * W_ELEMS;
        const uint16_t* WB1 = WB0 + W_ELEMS;

        // ---- weight slice -> regs, ONCE per pass, reused for both tiles ----
        bf16x8 w0[2][8], w1[2][8];
        #pragma unroll
        for (int ct = 0; ct < 2; ++ct) {
            const int wrow = colbase + ct * 16 + l15;
            #pragma unroll
            for (int kk = 0; kk < 8; ++kk) {
                if constexpr (WBF16) {
                    w0[ct][kk] = *(const bf16x8*)&WB0[(size_t)wrow * D_DIM + kk * 32 + quad * 8];
                    w1[ct][kk] = *(const bf16x8*)&WB1[(size_t)wrow * D_DIM + kk * 32 + quad * 8];
                } else {
                    w0[ct][kk] = cvt8(&WF0[(size_t)wrow * D_DIM + kk * 32 + quad * 8]);
                    w1[ct][kk] = cvt8(&WF1[(size_t)wrow * D_DIM + kk * 32 + quad * 8]);
                }
            }
        }

        f32x4 acc[2][2][4];   // [matrix][ct][nt]

        auto gemm = [&](int t) {
            #pragma unroll
            for (int m = 0; m < 2; ++m)
                #pragma unroll
                for (int ct = 0; ct < 2; ++ct)
                    #pragma unroll
                    for (int nt = 0; nt < 4; ++nt)
                        acc[m][ct][nt] = (f32x4){0.f, 0.f, 0.f, 0.f};
            #pragma unroll
            for (int kk = 0; kk < 8; ++kk) {
                const int k0 = kk * 32;
                bf16x8 ax[4];
                #pragma unroll
                for (int nt = 0; nt < 4; ++nt)
                    ax[nt] = *(const bf16x8*)&sX[t][(nt * 16 + l15) * SX_LD + k0 + quad * 8];
                #pragma unroll
                for (int ct = 0; ct < 2; ++ct)
                    #pragma unroll
                    for (int nt = 0; nt < 4; ++nt)
                        acc[0][ct][nt] = __builtin_amdgcn_mfma_f32_16x16x32_bf16(w0[ct][kk], ax[nt], acc[0][ct][nt], 0, 0, 0);
                #pragma unroll
                for (int ct = 0; ct < 2; ++ct)
                    #pragma unroll
                    for (int nt = 0; nt < 4; ++nt)
                        acc[1][ct][nt] = __builtin_amdgcn_mfma_f32_16x16x32_bf16(w1[ct][kk], ax[nt], acc[1][ct][nt], 0, 0, 0);
            }
        };

        auto qk_post = [&](int t) {
            // scores + softmax in-wave; neighbor j of token i is i^m, m=1..3
            #pragma unroll
            for (int nt = 0; nt < 4; ++nt) {
                float sc[3];
                #pragma unroll
                for (int m = 1; m <= 3; ++m) {
                    float s = 0.f;
                    #pragma unroll
                    for (int ct = 0; ct < 2; ++ct)
                        #pragma unroll
                        for (int r = 0; r < 4; ++r)
                            s += acc[0][ct][nt][r] * __shfl_xor(acc[1][ct][nt][r], m);
                    s += __shfl_xor(s, 16);
                    s += __shfl_xor(s, 32);
                    sc[m - 1] = s * SCALE_F;
                }
                const float mx = fmaxf(sc[0], fmaxf(sc[1], sc[2]));
                const float e1 = __expf(sc[0] - mx), e2 = __expf(sc[1] - mx), e3 = __expf(sc[2] - mx);
                const float inv = 1.f / (e1 + e2 + e3);
                const float am[3] = { e1 * inv, e2 * inv, e3 * inv };
                const int token = nt * 16 + l15;
                if (quad == 0) {
                    const int ii = token & 3;
                    float* al = &sALf[t][(token * H_NUM + h) * 3];
                    #pragma unroll
                    for (int l = 0; l < 3; ++l) {
                        const int jj = l + (l >= ii);
                        const int m  = ii ^ jj;
                        al[l] = am[m - 1];
                    }
                }
            }
        };

        auto v_post = [&]() {
            #pragma unroll
            for (int ct = 0; ct < 2; ++ct)
                #pragma unroll
                for (int nt = 0; nt < 4; ++nt)
                    #pragma unroll
                    for (int r = 0; r < 4; ++r)
                        acc[0][ct][nt][r] *= 1.f / (1.f + __expf(-acc[1][ct][nt][r]));
        };

        auto pv = [&](int t) {
            #pragma unroll
            for (int nt = 0; nt < 4; ++nt) {
                const int token = nt * 16 + l15;
                const int ii = token & 3;
                const float* al = &sALf[t][(token * H_NUM + h) * 3];
                float am[3];
                #pragma unroll
                for (int m = 1; m <= 3; ++m) {
                    const int jj = ii ^ m;
                    const int l  = jj - (jj > ii ? 1 : 0);
                    am[m - 1] = al[l];
                }
                #pragma unroll
                for (int ct = 0; ct < 2; ++ct) {
                    f32x4 ao;
                    #pragma unroll
                    for (int r = 0; r < 4; ++r) {
                        const float v = acc[0][ct][nt][r];
                        ao[r] = am[0] * __shfl_xor(v, 1)
                              + am[1] * __shfl_xor(v, 2)
                              + am[2] * __shfl_xor(v, 3);
                    }
                    *(uint2*)&sAO[t][token * AO_LD + colbase + ct * 16 + quad * 4] = pack4(ao);
                }
            }
        };

        // tile 0
        gemm(0);
        if (qk) qk_post(0); else v_post();
        __syncthreads();                   // alphas(t0) visible
        if (!qk) pv(0);                    // PV(t0) mixes with GEMM(t1) below
        // tile 1
        gemm(1);
        if (qk) qk_post(1); else v_post();
        __syncthreads();                   // alphas(t1) visible
        if (!qk) pv(1);                    // mixes with next pass's loadW+GEMM
    }

    // ---------------- Wo slice -> regs (once, used for both tiles) ----------
    bf16x8 wo_reg[2][8];
    {
        const uint16_t* WoB = wbf + (size_t)4 * W_ELEMS;
        #pragma unroll
        for (int ct = 0; ct < 2; ++ct) {
            const int wrow = wv * 32 + ct * 16 + l15;
            #pragma unroll
            for (int kk = 0; kk < 8; ++kk) {
                if constexpr (WBF16)
                    wo_reg[ct][kk] = *(const bf16x8*)&WoB[(size_t)wrow * D_DIM + kk * 32 + quad * 8];
                else
                    wo_reg[ct][kk] = cvt8(&Wo[(size_t)wrow * D_DIM + kk * 32 + quad * 8]);
            }
        }
    }
    __syncthreads();   // all sAO writes complete

    // ---------------- coalesced attn-prob store (both tiles) ----------------
    {
        const float* sa = &sALf[0][0];
        #pragma unroll
        for (int i = tid; i < 768; i += NTHR) {
            const float4 v = *(const float4*)&sa[i * 4];
            *(float4*)&outp[Y_SZ + (size_t)R0 * 24 + (size_t)i * 4] = v;
        }
    }

    // ---------------- AO @ Wo^T + residual + LN partials, both tiles --------
    f32x4 acc3[2][2][4];   // [tile][ct][nt]
    #pragma unroll
    for (int t = 0; t < 2; ++t) {
        #pragma unroll
        for (int ct = 0; ct < 2; ++ct)
            #pragma unroll
            for (int nt = 0; nt < 4; ++nt)
                acc3[t][ct][nt] = (f32x4){0.f, 0.f, 0.f, 0.f};

        #pragma unroll
        for (int kk = 0; kk < 8; ++kk) {
            const int k0 = kk * 32;
            bf16x8 ao[4];
            #pragma unroll
            for (int nt = 0; nt < 4; ++nt)
                ao[nt] = *(const bf16x8*)&sAO[t][(nt * 16 + l15) * AO_LD + k0 + quad * 8];
            #pragma unroll
            for (int ct = 0; ct < 2; ++ct)
                #pragma unroll
                for (int nt = 0; nt < 4; ++nt)
                    acc3[t][ct][nt] = __builtin_amdgcn_mfma_f32_16x16x32_bf16(wo_reg[ct][kk], ao[nt], acc3[t][ct][nt], 0, 0, 0);
        }

        #pragma unroll
        for (int nt = 0; nt < 4; ++nt) {
            const int token = nt * 16 + l15;
            float s1 = 0.f, s2 = 0.f;
            #pragma unroll
            for (int ct = 0; ct < 2; ++ct) {
                const ushort4 xv = *(const ushort4*)&sX[t][token * SX_LD + wv * 32 + ct * 16 + quad * 4];
                const float x0 = b2f(xv.x), x1 = b2f(xv.y), x2 = b2f(xv.z), x3 = b2f(xv.w);
                acc3[t][ct][nt][0] += x0; acc3[t][ct][nt][1] += x1;
                acc3[t][ct][nt][2] += x2; acc3[t][ct][nt][3] += x3;
                #pragma unroll
                for (int r = 0; r < 4; ++r) {
                    const float y = acc3[t][ct][nt][r];
                    s1 += y; s2 += y * y;
                }
            }
            s1 += __shfl_xor(s1, 16); s1 += __shfl_xor(s1, 32);
            s2 += __shfl_xor(s2, 16); s2 += __shfl_xor(s2, 32);
            if (quad == 0) {
                float2 ps; ps.x = s1; ps.y = s2;
                *(float2*)&sPT[t][token * SP_LD + wv * 2] = ps;
            }
        }
    }
    __syncthreads();

    // ---------------- LN finalize + store y, both tiles ----------------
    #pragma unroll
    for (int t = 0; t < 2; ++t) {
        #pragma unroll
        for (int nt = 0; nt < 4; ++nt) {
            const int token = nt * 16 + l15;
            const f32x4* pp = (const f32x4*)&sPT[t][token * SP_LD];
            const f32x4 q0 = pp[0], q1 = pp[1], q2 = pp[2], q3 = pp[3];
            const float s1 = q0[0] + q0[2] + q1[0] + q1[2] + q2[0] + q2[2] + q3[0] + q3[2];
            const float s2 = q0[1] + q0[3] + q1[1] + q1[3] + q2[1] + q2[3] + q3[1] + q3[3];
            const float mean = s1 * (1.f / 256.f);
            const float var  = fmaxf(s2 * (1.f / 256.f) - mean * mean, 0.f);
            const float rstd = rsqrtf(var + 1e-5f);
            float* orow = outp + (size_t)(R0 + t * RT + token) * D_DIM;
            #pragma unroll
            for (int ct = 0; ct < 2; ++ct) {
                const int c0 = wv * 32 + ct * 16 + quad * 4;
                const float4 g4 = *(const float4*)&lng[c0];
                const float4 b4 = *(const float4*)&lnb[c0];
                float4 o4;
                o4.x = (acc3[t][ct][nt][0] - mean) * rstd * g4.x + b4.x;
                o4.y = (acc3[t][ct][nt][1] - mean) * rstd * g4.y + b4.y;
                o4.z = (acc3[t][ct][nt][2] - mean) * rstd * g4.z + b4.z;
                o4.w = (acc3[t][ct][nt][3] - mean) * rstd * g4.w + b4.w;
                *(float4*)&orow[c0] = o4;
            }
        }
    }
}

extern "C" void kernel_launch(void* const* d_in, const int* in_sizes, int n_in,
                              void* d_out, int out_size, void* d_ws, size_t ws_size,
                              hipStream_t stream) {
    (void)in_sizes; (void)n_in; (void)out_size;
    const float* tok = (const float*)d_in[0];
    const float* Wq  = (const float*)d_in[1];
    const float* Wk  = (const float*)d_in[2];
    const float* Wv  = (const float*)d_in[3];
    const float* Wr  = (const float*)d_in[4];
    const float* Wo  = (const float*)d_in[5];
    const float* lng = (const float*)d_in[6];
    const float* lnb = (const float*)d_in[7];
    float* outp = (float*)d_out;
    uint16_t* wbf = (uint16_t*)d_ws;

    dim3 grid(ROWS_TOT / (2 * RT)), block(NTHR);
    if (ws_size >= (size_t)WS_NEED) {
        conv_weights<<<dim3(320), dim3(256), 0, stream>>>(Wq, Wk, Wv, Wr, Wo, wbf);
        cmaa_fused<true><<<grid, block, 0, stream>>>(
            tok, Wq, Wk, Wv, Wr, Wo, wbf, lng, lnb, outp);
    } else {
        cmaa_fused<false><<<grid, block, 0, stream>>>(
            tok, Wq, Wk, Wv, Wr, Wo, wbf, lng, lnb, outp);
    }
}